// Round 12
// baseline (346.097 us; speedup 1.0000x reference)
//
#include <hip/hip_runtime.h>
#include <hip/hip_bf16.h>

#define L_SEQ    1024
#define IN_DIM   256
#define DIM_MSA  32
#define PAIR_DIM 64
#define ISPLIT   8
#define ICHUNK   (L_SEQ / ISPLIT)   // 128
#define GRP      8                  // prefetch distance (named rotating regs)

// s[i][c] = b1[c] + sum_d seq[i][d] * W1[c][d]
__global__ void k_proj1(const float* __restrict__ seq, const float* __restrict__ W1,
                        const float* __restrict__ b1, float* __restrict__ s) {
    int t = blockIdx.x * blockDim.x + threadIdx.x;   // 1024*32 threads
    int i = t >> 5, c = t & 31;
    const float4* sq = (const float4*)(seq + i * IN_DIM);
    const float4* w  = (const float4*)(W1  + c * IN_DIM);
    float a0 = 0.f, a1 = 0.f, a2 = 0.f, a3 = 0.f;
#pragma unroll
    for (int d4 = 0; d4 < IN_DIM / 4; ++d4) {
        float4 x = sq[d4], y = w[d4];
        a0 += x.x * y.x;  a1 += x.y * y.y;
        a2 += x.z * y.z;  a3 += x.w * y.w;
    }
    s[t] = b1[c] + ((a0 + a1) + (a2 + a3));
}

// tmp[j][p][d] = sum_c s[j][c] * W2[p][c*32+d]   (thread computes 4 consecutive d)
__global__ void k_proj2(const float* __restrict__ s, const float* __restrict__ W2,
                        float* __restrict__ tmp) {
    int t = blockIdx.x * blockDim.x + threadIdx.x;   // 1024*64*8 threads
    int q = t & 7, p = (t >> 3) & 63, j = t >> 9;
    const float4* w  = (const float4*)W2;            // idx = p*256 + c*8 + q
    const float*  sj = s + j * DIM_MSA;
    float4 acc = {0.f, 0.f, 0.f, 0.f};
#pragma unroll
    for (int c = 0; c < DIM_MSA; ++c) {
        float  sc = sj[c];
        float4 wv = w[p * 256 + c * 8 + q];
        acc.x += sc * wv.x;  acc.y += sc * wv.y;
        acc.z += sc * wv.z;  acc.w += sc * wv.w;
    }
    ((float4*)tmp)[t] = acc;   // t = j*512 + p*8 + q  ==  [j][p][d] as float4
}

__device__ __forceinline__ float dot32(const float* __restrict__ srow,
    const float4 r0, const float4 r1, const float4 r2, const float4 r3,
    const float4 r4, const float4 r5, const float4 r6, const float4 r7) {
    const float4* sg = (const float4*)srow;           // wave-uniform -> s_load
    float4 s0 = sg[0], s1 = sg[1], s2 = sg[2], s3 = sg[3],
           s4 = sg[4], s5 = sg[5], s6 = sg[6], s7 = sg[7];
    float a0 = s0.x*r0.x + s0.y*r0.y + s0.z*r0.z + s0.w*r0.w
             + s1.x*r1.x + s1.y*r1.y + s1.z*r1.z + s1.w*r1.w;
    float a1 = s2.x*r2.x + s2.y*r2.y + s2.z*r2.z + s2.w*r2.w
             + s3.x*r3.x + s3.y*r3.y + s3.z*r3.z + s3.w*r3.w;
    float a2 = s4.x*r4.x + s4.y*r4.y + s4.z*r4.z + s4.w*r4.w
             + s5.x*r5.x + s5.y*r5.y + s5.z*r5.z + s5.w*r5.w;
    float a3 = s6.x*r6.x + s6.y*r6.y + s6.z*r6.z + s6.w*r6.w
             + s7.x*r7.x + s7.y*r7.y + s7.z*r7.z + s7.w*r7.w;
    return (a0 + a1) + (a2 + a3);
}

// CALIB A: known-good m13-pattern linear stream, genuine copy out <- pair.
// 256 MB read + 256 MB write, not DCE-able (distinct buffers).
__global__ __launch_bounds__(256) void k_stream_a(const float4* __restrict__ src,
                                                  float4* __restrict__ dst, size_t n4) {
    size_t x = (size_t)blockIdx.x * blockDim.x + threadIdx.x;
    size_t step = (size_t)gridDim.x * blockDim.x;
    for (; x < n4; x += step)
        dst[x] = src[x];
}

// CALIB B: byte-faithful clone of k_outer's MEMORY behavior (same grid, same
// j/chunk mapping, same 8-deep rotating prefetch at 256KB stride, same
// nt-stores) with the compute deleted: out <- pair element-wise.
__global__ __launch_bounds__(256) void k_stream_b(const float* __restrict__ pair,
                                                  float* __restrict__ out) {
    int tid  = threadIdx.x;
    int wave = tid >> 6, lane = tid & 63;
    int jgrp  = blockIdx.x & 255;
    int chunk = blockIdx.x >> 8;
    int j  = jgrp * 4 + wave;
    int i0 = chunk * ICHUNK;

    const size_t stride = (size_t)L_SEQ * PAIR_DIM;              // 65536
    const float* pr = pair + ((size_t)i0 * L_SEQ + j) * PAIR_DIM + lane;
    float*       po = out  + ((size_t)i0 * L_SEQ + j) * PAIR_DIM + lane;

    float pv0 = pr[0 * stride], pv1 = pr[1 * stride],
          pv2 = pr[2 * stride], pv3 = pr[3 * stride],
          pv4 = pr[4 * stride], pv5 = pr[5 * stride],
          pv6 = pr[6 * stride], pv7 = pr[7 * stride];
    pr += (size_t)GRP * stride;

#define BSTEP(PV) do {                                                        \
        __builtin_nontemporal_store((PV), po); po += stride;                  \
        (PV) = *pr; pr += stride;                                             \
    } while (0)
#define BSTEPL(PV) do {                                                       \
        __builtin_nontemporal_store((PV), po); po += stride;                  \
    } while (0)

#pragma unroll 1
    for (int g = 0; g < ICHUNK / GRP - 1; ++g) {
        BSTEP(pv0); BSTEP(pv1); BSTEP(pv2); BSTEP(pv3);
        BSTEP(pv4); BSTEP(pv5); BSTEP(pv6); BSTEP(pv7);
    }
    BSTEPL(pv0); BSTEPL(pv1); BSTEPL(pv2); BSTEPL(pv3);
    BSTEPL(pv4); BSTEPL(pv5); BSTEPL(pv6); BSTEPL(pv7);
#undef BSTEP
#undef BSTEPL
}

// out[i][j][p] = sum_d s[i][d]*tmp[j][p][d] + b2[p] + pair[i][j][p]
// (byte-identical to R8 — runs LAST so the final output is correct)
__global__ __launch_bounds__(256) void k_outer(
    const float* __restrict__ s, const float* __restrict__ tmp,
    const float* __restrict__ pair, const float* __restrict__ b2,
    float* __restrict__ out) {
    int tid  = threadIdx.x;
    int wave = tid >> 6, lane = tid & 63;
    int jgrp  = blockIdx.x & 255;               // 256 j-groups of 4
    int chunk = blockIdx.x >> 8;                // ISPLIT i-chunks
    int j  = jgrp * 4 + wave;
    int i0 = chunk * ICHUNK;

    const float4* tj = (const float4*)(tmp + (size_t)(j * PAIR_DIM + lane) * DIM_MSA);
    float4 r0 = tj[0], r1 = tj[1], r2 = tj[2], r3 = tj[3],
           r4 = tj[4], r5 = tj[5], r6 = tj[6], r7 = tj[7];
    float bias = b2[lane];

    const size_t stride = (size_t)L_SEQ * PAIR_DIM;              // 65536
    const float* pr = pair + ((size_t)i0 * L_SEQ + j) * PAIR_DIM + lane;
    float*       po = out  + ((size_t)i0 * L_SEQ + j) * PAIR_DIM + lane;

    float pv0 = pr[0 * stride], pv1 = pr[1 * stride],
          pv2 = pr[2 * stride], pv3 = pr[3 * stride],
          pv4 = pr[4 * stride], pv5 = pr[5 * stride],
          pv6 = pr[6 * stride], pv7 = pr[7 * stride];
    pr += (size_t)GRP * stride;

    int ii = i0;

#define STEP(PV) do {                                                         \
        float dv = dot32(s + (size_t)ii * DIM_MSA, r0,r1,r2,r3,r4,r5,r6,r7);  \
        __builtin_nontemporal_store(dv + bias + (PV), po); po += stride;      \
        (PV) = *pr; pr += stride; ++ii;                                       \
    } while (0)

#define STEPL(PV) do {                                                        \
        float dv = dot32(s + (size_t)ii * DIM_MSA, r0,r1,r2,r3,r4,r5,r6,r7);  \
        __builtin_nontemporal_store(dv + bias + (PV), po); po += stride;      \
        ++ii;                                                                 \
    } while (0)

#pragma unroll 1
    for (int g = 0; g < ICHUNK / GRP - 1; ++g) {
        STEP(pv0); STEP(pv1); STEP(pv2); STEP(pv3);
        STEP(pv4); STEP(pv5); STEP(pv6); STEP(pv7);
    }
    STEPL(pv0); STEPL(pv1); STEPL(pv2); STEPL(pv3);
    STEPL(pv4); STEPL(pv5); STEPL(pv6); STEPL(pv7);

#undef STEP
#undef STEPL
}

extern "C" void kernel_launch(void* const* d_in, const int* in_sizes, int n_in,
                              void* d_out, int out_size, void* d_ws, size_t ws_size,
                              hipStream_t stream) {
    const float* seq  = (const float*)d_in[0];   // [1,1024,256]
    const float* pair = (const float*)d_in[1];   // [1,1024,1024,64]
    const float* W1   = (const float*)d_in[2];   // [32,256]
    const float* b1   = (const float*)d_in[3];   // [32]
    const float* W2   = (const float*)d_in[4];   // [64,1024]
    const float* b2   = (const float*)d_in[5];   // [64]
    float* out = (float*)d_out;

    float* s_ws   = (float*)d_ws;                         // 1024*32   = 128 KB
    float* tmp_ws = s_ws + (size_t)L_SEQ * DIM_MSA;       // 1024*64*32 = 8 MB

    k_proj1<<<(L_SEQ * DIM_MSA) / 256, 256, 0, stream>>>(seq, W1, b1, s_ws);
    k_proj2<<<(L_SEQ * PAIR_DIM * (DIM_MSA / 4)) / 256, 256, 0, stream>>>(s_ws, W2, tmp_ws);
    // calibration dispatches (out is fully rewritten by k_outer afterwards)
    k_stream_b<<<256 * ISPLIT, 256, 0, stream>>>(pair, out);
    k_stream_a<<<2048, 256, 0, stream>>>((const float4*)pair, (float4*)out,
                                         (size_t)out_size / 4);
    k_outer<<<256 * ISPLIT, 256, 0, stream>>>(s_ws, tmp_ws, pair, b2, out);
}

// Round 13
// 276.530 us; speedup vs baseline: 1.2516x; 1.2516x over previous
//
#include <hip/hip_runtime.h>
#include <hip/hip_bf16.h>

#define L_SEQ    1024
#define IN_DIM   256
#define DIM_MSA  32
#define PAIR_DIM 64
#define JCHUNK   128                 // j's per block walk

typedef float f4v __attribute__((ext_vector_type(4)));

// s[i][c] = b1[c] + sum_d seq[i][d] * W1[c][d]
__global__ void k_proj1(const float* __restrict__ seq, const float* __restrict__ W1,
                        const float* __restrict__ b1, float* __restrict__ s) {
    int t = blockIdx.x * blockDim.x + threadIdx.x;   // 1024*32 threads
    int i = t >> 5, c = t & 31;
    const float4* sq = (const float4*)(seq + i * IN_DIM);
    const float4* w  = (const float4*)(W1  + c * IN_DIM);
    float a0 = 0.f, a1 = 0.f, a2 = 0.f, a3 = 0.f;
#pragma unroll
    for (int d4 = 0; d4 < IN_DIM / 4; ++d4) {
        float4 x = sq[d4], y = w[d4];
        a0 += x.x * y.x;  a1 += x.y * y.y;
        a2 += x.z * y.z;  a3 += x.w * y.w;
    }
    s[t] = b1[c] + ((a0 + a1) + (a2 + a3));
}

// tmpP[j][dg][p][dl] = tmp[j][p][dg*4+dl] = sum_c s[j][c] * W2[p][c*32+dg*4+dl]
// (f4 store index j*512 + dg*64 + p -> per-(j,dg) slab is 1KB contiguous over p)
__global__ void k_proj2(const float* __restrict__ s, const float* __restrict__ W2,
                        float* __restrict__ tmpP) {
    int t = blockIdx.x * blockDim.x + threadIdx.x;   // 1024*64*8 threads
    int q = t & 7, p = (t >> 3) & 63, j = t >> 9;
    const float4* w  = (const float4*)W2;            // f4 idx p*256+c*8+q = d 4q..4q+3
    const float*  sj = s + j * DIM_MSA;
    float4 acc = {0.f, 0.f, 0.f, 0.f};
#pragma unroll
    for (int c = 0; c < DIM_MSA; ++c) {
        float  sc = sj[c];
        float4 wv = w[p * 256 + c * 8 + q];
        acc.x += sc * wv.x;  acc.y += sc * wv.y;
        acc.z += sc * wv.z;  acc.w += sc * wv.w;
    }
    f4v o; o.x = acc.x; o.y = acc.y; o.z = acc.z; o.w = acc.w;
    ((f4v*)tmpP)[j * 512 + q * 64 + p] = o;
}

// out[i][j][p] = sum_d s[i][d]*tmp[j][p][d] + b2[p] + pair[i][j][p]
// LINEAR-STREAM version: lane = p; wave owns i0,i0+1 (s rows in SGPRs) and
// WALKS J (+256B/step) -> pair loads & out stores are sequentially-advancing
// DRAM streams (row-buffer hits), unlike all prior i-walking variants.
// tmp[j] comes from L2/L1 as 8 x 1KB contiguous loads per j.
__global__ __launch_bounds__(256) void k_outer(
    const float* __restrict__ s, const float* __restrict__ tmpP,
    const float* __restrict__ pair, const float* __restrict__ b2,
    float* __restrict__ out) {
    int tid  = threadIdx.x;
    int wave = tid >> 6, lane = tid & 63;        // lane = p
    int ib = blockIdx.x >> 3;                    // 128 i-octets
    int jc = blockIdx.x & 7;                     // 8 j-chunks
    int i0 = ib * 8 + wave * 2;                  // wave's two i
    int j0 = jc * JCHUNK;

    // s rows (wave-uniform) -> SGPRs via s_load (proven R7/R8)
    const float4* sA4 = (const float4*)(s + (size_t)i0 * DIM_MSA);
    const float4* sB4 = (const float4*)(s + (size_t)(i0 + 1) * DIM_MSA);
    float4 a0 = sA4[0], a1 = sA4[1], a2 = sA4[2], a3 = sA4[3],
           a4 = sA4[4], a5 = sA4[5], a6 = sA4[6], a7 = sA4[7];
    float4 b0 = sB4[0], b1 = sB4[1], b2v = sB4[2], b3 = sB4[3],
           b4 = sB4[4], b5 = sB4[5], b6 = sB4[6], b7 = sB4[7];
    float bias = b2[lane];

    const f4v* tp = (const f4v*)tmpP + (size_t)j0 * 512 + lane;
    const size_t irow = (size_t)L_SEQ * PAIR_DIM;           // 65536
    const float* prA = pair + (size_t)i0 * irow + (size_t)j0 * PAIR_DIM + lane;
    const float* prB = prA + irow;
    float* poA = out + (size_t)i0 * irow + (size_t)j0 * PAIR_DIM + lane;
    float* poB = poA + irow;

    // prologue: tmp[j0] + pair depth-4
    f4v t0 = tp[0], t1 = tp[64], t2 = tp[128], t3 = tp[192],
        t4 = tp[256], t5 = tp[320], t6 = tp[384], t7 = tp[448];
    float pA0 = prA[0],   pB0 = prB[0],
          pA1 = prA[64],  pB1 = prB[64],
          pA2 = prA[128], pB2 = prB[128],
          pA3 = prA[192], pB3 = prB[192];

#pragma unroll 2
    for (int j = 0; j < JCHUNK; ++j) {
        f4v n0 = t0, n1 = t1, n2 = t2, n3 = t3,
            n4 = t4, n5 = t5, n6 = t6, n7 = t7;
        if (j < JCHUNK - 1) {                    // prefetch tmp[j+1] (L1/L2)
            const f4v* tn = tp + (size_t)(j + 1) * 512;
            n0 = tn[0];   n1 = tn[64];  n2 = tn[128]; n3 = tn[192];
            n4 = tn[256]; n5 = tn[320]; n6 = tn[384]; n7 = tn[448];
        }
        float qA = 0.f, qB = 0.f;
        if (j < JCHUNK - 4) {                    // prefetch pair[j+4] (HBM, linear)
            qA = prA[(size_t)(j + 4) * PAIR_DIM];
            qB = prB[(size_t)(j + 4) * PAIR_DIM];
        }
        float xA0 = t0.x*a0.x + t0.y*a0.y + t0.z*a0.z + t0.w*a0.w
                  + t1.x*a1.x + t1.y*a1.y + t1.z*a1.z + t1.w*a1.w;
        float xA1 = t2.x*a2.x + t2.y*a2.y + t2.z*a2.z + t2.w*a2.w
                  + t3.x*a3.x + t3.y*a3.y + t3.z*a3.z + t3.w*a3.w;
        float xA2 = t4.x*a4.x + t4.y*a4.y + t4.z*a4.z + t4.w*a4.w
                  + t5.x*a5.x + t5.y*a5.y + t5.z*a5.z + t5.w*a5.w;
        float xA3 = t6.x*a6.x + t6.y*a6.y + t6.z*a6.z + t6.w*a6.w
                  + t7.x*a7.x + t7.y*a7.y + t7.z*a7.z + t7.w*a7.w;
        float xB0 = t0.x*b0.x + t0.y*b0.y + t0.z*b0.z + t0.w*b0.w
                  + t1.x*b1.x + t1.y*b1.y + t1.z*b1.z + t1.w*b1.w;
        float xB1 = t2.x*b2v.x + t2.y*b2v.y + t2.z*b2v.z + t2.w*b2v.w
                  + t3.x*b3.x + t3.y*b3.y + t3.z*b3.z + t3.w*b3.w;
        float xB2 = t4.x*b4.x + t4.y*b4.y + t4.z*b4.z + t4.w*b4.w
                  + t5.x*b5.x + t5.y*b5.y + t5.z*b5.z + t5.w*b5.w;
        float xB3 = t6.x*b6.x + t6.y*b6.y + t6.z*b6.z + t6.w*b6.w
                  + t7.x*b7.x + t7.y*b7.y + t7.z*b7.z + t7.w*b7.w;
        __builtin_nontemporal_store(((xA0 + xA1) + (xA2 + xA3)) + bias + pA0,
                                    poA + (size_t)j * PAIR_DIM);
        __builtin_nontemporal_store(((xB0 + xB1) + (xB2 + xB3)) + bias + pB0,
                                    poB + (size_t)j * PAIR_DIM);
        pA0 = pA1; pA1 = pA2; pA2 = pA3; pA3 = qA;
        pB0 = pB1; pB1 = pB2; pB2 = pB3; pB3 = qB;
        t0 = n0; t1 = n1; t2 = n2; t3 = n3;
        t4 = n4; t5 = n5; t6 = n6; t7 = n7;
    }
}

extern "C" void kernel_launch(void* const* d_in, const int* in_sizes, int n_in,
                              void* d_out, int out_size, void* d_ws, size_t ws_size,
                              hipStream_t stream) {
    const float* seq  = (const float*)d_in[0];   // [1,1024,256]
    const float* pair = (const float*)d_in[1];   // [1,1024,1024,64]
    const float* W1   = (const float*)d_in[2];   // [32,256]
    const float* b1   = (const float*)d_in[3];   // [32]
    const float* W2   = (const float*)d_in[4];   // [64,1024]
    const float* b2   = (const float*)d_in[5];   // [64]
    float* out = (float*)d_out;

    float* s_ws   = (float*)d_ws;                         // 1024*32   = 128 KB
    float* tmp_ws = s_ws + (size_t)L_SEQ * DIM_MSA;       // tmpP, 8 MB

    k_proj1<<<(L_SEQ * DIM_MSA) / 256, 256, 0, stream>>>(seq, W1, b1, s_ws);
    k_proj2<<<(L_SEQ * PAIR_DIM * (DIM_MSA / 4)) / 256, 256, 0, stream>>>(s_ws, W2, tmp_ws);
    k_outer<<<128 * 8, 256, 0, stream>>>(s_ws, tmp_ws, pair, b2, out);
}

// Round 14
// 112.227 us; speedup vs baseline: 3.0839x; 2.4640x over previous
//
#include <hip/hip_runtime.h>
#include <hip/hip_bf16.h>

#define L_SEQ    1024
#define IN_DIM   256
#define DIM_MSA  32
#define PAIR_DIM 64

typedef float f4 __attribute__((ext_vector_type(4)));
typedef short s8 __attribute__((ext_vector_type(8)));

__device__ __forceinline__ unsigned short f2bf(float f) {
    unsigned u = __float_as_uint(f);
    u = (u + 0x7FFFu + ((u >> 16) & 1u)) >> 16;   // RNE
    return (unsigned short)u;
}

// s[i][c] = b1[c] + sum_d seq[i][d] * W1[c][d]  (fp32 + bf16 copies)
__global__ void k_proj1(const float* __restrict__ seq, const float* __restrict__ W1,
                        const float* __restrict__ b1, float* __restrict__ s,
                        unsigned short* __restrict__ s_bf) {
    int t = blockIdx.x * blockDim.x + threadIdx.x;   // 1024*32 threads
    int i = t >> 5, c = t & 31;
    const float4* sq = (const float4*)(seq + i * IN_DIM);
    const float4* w  = (const float4*)(W1  + c * IN_DIM);
    float a0 = 0.f, a1 = 0.f, a2 = 0.f, a3 = 0.f;
#pragma unroll
    for (int d4 = 0; d4 < IN_DIM / 4; ++d4) {
        float4 x = sq[d4], y = w[d4];
        a0 += x.x * y.x;  a1 += x.y * y.y;
        a2 += x.z * y.z;  a3 += x.w * y.w;
    }
    float v = b1[c] + ((a0 + a1) + (a2 + a3));
    s[t]    = v;
    s_bf[t] = f2bf(v);
}

// tmp_bf[jp][d] = bf16( sum_c s[j][c] * W2[p][c*32+d] ), jp = j*64+p
__global__ void k_proj2(const float* __restrict__ s, const float* __restrict__ W2,
                        unsigned short* __restrict__ tmp_bf) {
    int t = blockIdx.x * blockDim.x + threadIdx.x;   // 1024*64*8 threads
    int q = t & 7, p = (t >> 3) & 63, j = t >> 9;
    const float4* w  = (const float4*)W2;            // idx = p*256 + c*8 + q
    const float*  sj = s + j * DIM_MSA;
    float4 acc = {0.f, 0.f, 0.f, 0.f};
#pragma unroll
    for (int c = 0; c < DIM_MSA; ++c) {
        float  sc = sj[c];
        float4 wv = w[p * 256 + c * 8 + q];
        acc.x += sc * wv.x;  acc.y += sc * wv.y;
        acc.z += sc * wv.z;  acc.w += sc * wv.w;
    }
    ushort4 o;
    o.x = f2bf(acc.x);  o.y = f2bf(acc.y);
    o.z = f2bf(acc.z);  o.w = f2bf(acc.w);
    ((ushort4*)tmp_bf)[t] = o;   // shorts 4t..4t+3 == [jp][d] row-major
}

// out[i][jp] = MFMA(s_bf, tmp_bf) + b2 + pair, with LDS-transposed epilogue.
// Block = i-tile(16) x jp-block(1024). Wave w owns jp0 = jb*1024+w*256 (256 jp)
// and a private 16KB LDS slab. Phase 1: 16 MFMA tiles (16 jp each); C written
// to LDS at [i_loc][jp_loc]. Phase 2: per i-row, lane l handles f4 jp_loc=4l:
// pair load + LDS read + add + nt store are 1KB contiguous per instruction
// (block: 4KB contiguous per i-row). No barriers (wave-private LDS).
// A/B/C lane-mapping identical to R10 (HW-verified: passed absmax 0.0625).
__global__ __launch_bounds__(256) void k_outer_mfma2(
    const unsigned short* __restrict__ s_bf, const unsigned short* __restrict__ tmp_bf,
    const float* __restrict__ pair, const float* __restrict__ b2,
    float* __restrict__ out) {
    __shared__ float lds[4 * 16 * 256];          // 64 KB
    int tid = threadIdx.x;
    int w = tid >> 6, l = tid & 63;
    int n = l & 15, kg = l >> 4;
    int jb = blockIdx.x & 63;                    // jp-block fast axis
    int it = blockIdx.x >> 6;                    // i-tile

    // A-frag: s_bf[it*16 + n][kg*8 .. +7]
    s8 a = *(const s8*)(s_bf + (size_t)(it * 16 + n) * DIM_MSA + kg * 8);

    int jp0 = jb * 1024 + w * 256;               // wave's jp range
    const unsigned short* bp = tmp_bf + (size_t)(jp0 + n) * DIM_MSA + kg * 8;
    float* myl = lds + w * 4096;                 // wave-private 16 KB

#pragma unroll
    for (int t = 0; t < 16; ++t) {
        s8 b = *(const s8*)(bp + (size_t)t * 16 * DIM_MSA);  // 1KB/wave, L2
        f4 z = {0.f, 0.f, 0.f, 0.f};
        f4 c = __builtin_amdgcn_mfma_f32_16x16x32_bf16(a, b, z, 0, 0, 0);
        // C: reg r -> i_loc = kg*4 + r, jp_loc = t*16 + n
        float* dst = myl + (kg * 4) * 256 + t * 16 + n;
        dst[0]   = c.x;
        dst[256] = c.y;
        dst[512] = c.z;
        dst[768] = c.w;
    }
    // same-wave RAW through LDS: compiler inserts lgkmcnt wait; no barrier.

    f4 b4 = *(const f4*)(b2 + ((l * 4) & 63));
    size_t rowbase = (size_t)(it * 16) * 65536 + (size_t)jp0 + l * 4;
    const float* pp = pair + rowbase;
    float*       op = out  + rowbase;

#pragma unroll 8
    for (int i = 0; i < 16; ++i) {
        f4 cc = *(const f4*)(myl + i * 256 + l * 4);
        f4 pv = *(const f4*)(pp + (size_t)i * 65536);        // 1KB/wave contiguous
        f4 o  = cc + b4 + pv;
        __builtin_nontemporal_store(o, (f4*)(op + (size_t)i * 65536));
    }
}

extern "C" void kernel_launch(void* const* d_in, const int* in_sizes, int n_in,
                              void* d_out, int out_size, void* d_ws, size_t ws_size,
                              hipStream_t stream) {
    const float* seq  = (const float*)d_in[0];   // [1,1024,256]
    const float* pair = (const float*)d_in[1];   // [1,1024,1024,64]
    const float* W1   = (const float*)d_in[2];   // [32,256]
    const float* b1   = (const float*)d_in[3];   // [32]
    const float* W2   = (const float*)d_in[4];   // [64,1024]
    const float* b2   = (const float*)d_in[5];   // [64]
    float* out = (float*)d_out;

    float*          s_ws = (float*)d_ws;                     // 128 KB fp32
    unsigned short* sbf  = (unsigned short*)(s_ws + 32768);  // 64 KB bf16
    unsigned short* tbf  = sbf + 32768;                      // 4 MB bf16 [jp][d]

    k_proj1<<<(L_SEQ * DIM_MSA) / 256, 256, 0, stream>>>(seq, W1, b1, s_ws, sbf);
    k_proj2<<<(L_SEQ * PAIR_DIM * (DIM_MSA / 4)) / 256, 256, 0, stream>>>(s_ws, W2, tbf);
    k_outer_mfma2<<<64 * 64, 256, 0, stream>>>(sbf, tbf, pair, b2, out);
}